// Round 1
// baseline (3333.976 us; speedup 1.0000x reference)
//
#include <hip/hip_runtime.h>
#include <math.h>

// DeepArcNet fused kernel: depthwise conv encode -> pos-embed -> 2x tiny
// transformer layers (seq=6, embd=68, heads=2x34) -> final LN -> FC head.
//
// Mapping: one wave = 10 items, one lane = (item, token c in 0..5); lanes
// 60..63 idle (clamped). Per-lane state in registers; weights read as
// wave-uniform scalar loads; cross-token attention via __shfl (in-wave).
// No LDS, no __syncthreads.

#define EMBD 68
#define NTOK 6
#define HEADD 34

__device__ __forceinline__ void ln68(const float* yv, float* hv,
                                     const float* g, const float* b) {
    float s1 = 0.f;
#pragma unroll
    for (int e = 0; e < EMBD; ++e) s1 += yv[e];
    const float m = s1 * (1.0f / 68.0f);
    float s2 = 0.f;
#pragma unroll
    for (int e = 0; e < EMBD; ++e) { const float d = yv[e] - m; s2 = fmaf(d, d, s2); }
    const float rs = rsqrtf(s2 * (1.0f / 68.0f) + 1e-5f);
#pragma unroll
    for (int e = 0; e < EMBD; ++e) hv[e] = (yv[e] - m) * rs * g[e] + b[e];
}

__global__ __launch_bounds__(256, 1)
void deeparcnet_fused(const float* __restrict__ x,        // [B,6,37,5]
                      const float* __restrict__ conv_w,   // [6,1,5,5]
                      const float* __restrict__ conv_b,   // [6]
                      const float* __restrict__ lemb_w,   // [6,4]
                      const float* __restrict__ lemb_b,   // [6,4]
                      const float* __restrict__ wq,       // [2,2,34,68]
                      const float* __restrict__ wk,       // [2,2,34,68]
                      const float* __restrict__ wv,       // [2,2,34,68]
                      const float* __restrict__ proj_w,   // [2,68,68]
                      const float* __restrict__ proj_b,   // [2,68]
                      const float* __restrict__ ff1_w,    // [2,34,68]
                      const float* __restrict__ ff1_b,    // [2,34]
                      const float* __restrict__ ff2_w,    // [2,68,34]
                      const float* __restrict__ ff2_b,    // [2,68]
                      const float* __restrict__ ln1_g, const float* __restrict__ ln1_b,
                      const float* __restrict__ ln2_g, const float* __restrict__ ln2_b,
                      const float* __restrict__ lnf_g, const float* __restrict__ lnf_b,
                      const float* __restrict__ fc_w,     // [6,408]
                      const float* __restrict__ fc_b,     // [6]
                      float* __restrict__ out,            // [B,6]
                      int B)
{
    const int lane = threadIdx.x & 63;
    const int wid  = blockIdx.x * (blockDim.x >> 6) + (threadIdx.x >> 6);
    const int sub  = lane / 6;          // item slot within wave: 0..10
    const int c    = lane - sub * 6;    // token / conv channel: 0..5
    const int item = wid * 10 + sub;
    const bool active = (sub < 10) && (item < B);
    const int it = active ? item : 0;   // clamp for safe loads
    const int base_lane = sub * 6;      // first lane of my 6-lane item group

    // ---------------- conv encode: [37,5] -> relu -> xc[17] ----------------
    float xw[25];
#pragma unroll
    for (int k = 0; k < 25; ++k) xw[k] = conv_w[c * 25 + k];
    const float cb = conv_b[c];
    const float* xp = x + (size_t)(it * 6 + c) * 185;

    float xc[17];
#pragma unroll
    for (int i = 0; i < 17; ++i) {
        float a = cb;
#pragma unroll
        for (int k = 0; k < 25; ++k) a = fmaf(xp[i * 10 + k], xw[k], a);
        xc[i] = fmaxf(a, 0.0f);
    }

    // ---------------- linear embed (1->4) + sinusoidal pos ----------------
    const float lw0 = lemb_w[c * 4 + 0], lw1 = lemb_w[c * 4 + 1];
    const float lw2 = lemb_w[c * 4 + 2], lw3 = lemb_w[c * 4 + 3];
    const float lb0 = lemb_b[c * 4 + 0], lb1 = lemb_b[c * 4 + 1];
    const float lb2 = lemb_b[c * 4 + 2], lb3 = lemb_b[c * 4 + 3];

    float h[EMBD];
#pragma unroll
    for (int t = 0; t < 17; ++t) {
        const float tf = (float)t;
        const float a1 = tf * (1.0f / 18.0f);   // freqs = [1, 1/18]
        h[4 * t + 0] = fmaf(xc[t], lw0, lb0) + __sinf(tf);
        h[4 * t + 1] = fmaf(xc[t], lw1, lb1) + __sinf(a1);
        h[4 * t + 2] = fmaf(xc[t], lw2, lb2) + __cosf(tf);
        h[4 * t + 3] = fmaf(xc[t], lw3, lb3) + __cosf(a1);
    }

    const float qscale = 0.16903085094570331f;  // 34^-0.5

    // ---------------- 2 transformer layers (loop kept rolled) --------------
#pragma unroll 1
    for (int l = 0; l < 2; ++l) {
        const float* Wq = wq + l * (2 * HEADD * EMBD);
        const float* Wk = wk + l * (2 * HEADD * EMBD);
        const float* Wv = wv + l * (2 * HEADD * EMBD);
        const float* Pw = proj_w + l * (EMBD * EMBD);
        const float* Pb = proj_b + l * EMBD;
        const float* W1 = ff1_w + l * (HEADD * EMBD);
        const float* b1 = ff1_b + l * HEADD;
        const float* W2 = ff2_w + l * (EMBD * HEADD);
        const float* b2 = ff2_b + l * EMBD;
        const float* g1 = ln1_g + l * EMBD; const float* e1 = ln1_b + l * EMBD;
        const float* g2 = ln2_g + l * EMBD; const float* e2 = ln2_b + l * EMBD;

        // q (scaled) and k for both heads: o = head*34 + d
        float q[EMBD], kv[EMBD];
#pragma unroll
        for (int o = 0; o < EMBD; ++o) {
            float aq = 0.f, ak = 0.f;
#pragma unroll
            for (int e = 0; e < EMBD; ++e) {
                aq = fmaf(h[e], Wq[o * EMBD + e], aq);
                ak = fmaf(h[e], Wk[o * EMBD + e], ak);
            }
            q[o]  = aq * qscale;
            kv[o] = ak;
        }

        // scores + softmax (k of token s pulled via shfl from lane base+s)
        float wei[2][NTOK];
#pragma unroll
        for (int hh = 0; hh < 2; ++hh) {
            float sc[NTOK];
#pragma unroll
            for (int s = 0; s < NTOK; ++s) {
                float a = 0.f;
#pragma unroll
                for (int d = 0; d < HEADD; ++d) {
                    const float ks = __shfl(kv[hh * HEADD + d], base_lane + s, 64);
                    a = fmaf(q[hh * HEADD + d], ks, a);
                }
                sc[s] = a;
            }
            float m = sc[0];
#pragma unroll
            for (int s = 1; s < NTOK; ++s) m = fmaxf(m, sc[s]);
            float sum = 0.f;
#pragma unroll
            for (int s = 0; s < NTOK; ++s) { sc[s] = __expf(sc[s] - m); sum += sc[s]; }
            const float r = 1.0f / sum;
#pragma unroll
            for (int s = 0; s < NTOK; ++s) wei[hh][s] = sc[s] * r;
        }

        // v (overwrites kv)
#pragma unroll
        for (int o = 0; o < EMBD; ++o) {
            float av = 0.f;
#pragma unroll
            for (int e = 0; e < EMBD; ++e) av = fmaf(h[e], Wv[o * EMBD + e], av);
            kv[o] = av;
        }

        // attn out (concat-heads order = h*34+d), into q registers
#pragma unroll
        for (int hh = 0; hh < 2; ++hh) {
#pragma unroll
            for (int d = 0; d < HEADD; ++d) {
                float a = 0.f;
#pragma unroll
                for (int s = 0; s < NTOK; ++s) {
                    const float vs = __shfl(kv[hh * HEADD + d], base_lane + s, 64);
                    a = fmaf(wei[hh][s], vs, a);
                }
                q[hh * HEADD + d] = a;
            }
        }

        // proj + residual, then LN1 -> h
        float y[EMBD];
#pragma unroll
        for (int o = 0; o < EMBD; ++o) {
            float a = Pb[o];
#pragma unroll
            for (int e = 0; e < EMBD; ++e) a = fmaf(q[e], Pw[o * EMBD + e], a);
            y[o] = h[o] + a;
        }
        ln68(y, h, g1, e1);

        // ff1 (relu), z kept in registers
        float z[HEADD];
#pragma unroll
        for (int f = 0; f < HEADD; ++f) {
            float a = b1[f];
#pragma unroll
            for (int e = 0; e < EMBD; ++e) a = fmaf(h[e], W1[f * EMBD + e], a);
            z[f] = fmaxf(a, 0.f);
        }

        // ff2 + residual, then LN2 -> h
#pragma unroll
        for (int o = 0; o < EMBD; ++o) {
            float a = b2[o];
#pragma unroll
            for (int f = 0; f < HEADD; ++f) a = fmaf(z[f], W2[o * HEADD + f], a);
            y[o] = h[o] + a;
        }
        ln68(y, h, g2, e2);
    }

    // ---------------- final LN ----------------
    ln68(h, h, lnf_g, lnf_b);

    // ---------------- fc head: out[o] = relu(sum_{c,e} h * fc_w) ----------
    float p[NTOK];
#pragma unroll
    for (int o = 0; o < NTOK; ++o) {
        float a = 0.f;
#pragma unroll
        for (int e = 0; e < EMBD; ++e)
            a = fmaf(h[e], fc_w[o * 408 + c * EMBD + e], a);
        p[o] = a;
    }
    float tot[NTOK];
#pragma unroll
    for (int o = 0; o < NTOK; ++o) {
        float a = 0.f;
#pragma unroll
        for (int t = 0; t < NTOK; ++t) a += __shfl(p[o], base_lane + t, 64);
        tot[o] = a + fc_b[o];
    }
    float myout = tot[0];
    if (c == 1) myout = tot[1];
    if (c == 2) myout = tot[2];
    if (c == 3) myout = tot[3];
    if (c == 4) myout = tot[4];
    if (c == 5) myout = tot[5];
    if (active) out[(size_t)item * 6 + c] = fmaxf(myout, 0.f);
}

extern "C" void kernel_launch(void* const* d_in, const int* in_sizes, int n_in,
                              void* d_out, int out_size, void* d_ws, size_t ws_size,
                              hipStream_t stream) {
    const float* x      = (const float*)d_in[0];
    const float* conv_w = (const float*)d_in[1];
    const float* conv_b = (const float*)d_in[2];
    const float* lemb_w = (const float*)d_in[3];
    const float* lemb_b = (const float*)d_in[4];
    const float* wq     = (const float*)d_in[5];
    const float* wk     = (const float*)d_in[6];
    const float* wv     = (const float*)d_in[7];
    const float* proj_w = (const float*)d_in[8];
    const float* proj_b = (const float*)d_in[9];
    const float* ff1_w  = (const float*)d_in[10];
    const float* ff1_b  = (const float*)d_in[11];
    const float* ff2_w  = (const float*)d_in[12];
    const float* ff2_b  = (const float*)d_in[13];
    const float* ln1_g  = (const float*)d_in[14];
    const float* ln1_b  = (const float*)d_in[15];
    const float* ln2_g  = (const float*)d_in[16];
    const float* ln2_b  = (const float*)d_in[17];
    const float* lnf_g  = (const float*)d_in[18];
    const float* lnf_b  = (const float*)d_in[19];
    const float* fc_w   = (const float*)d_in[20];
    const float* fc_b   = (const float*)d_in[21];
    float* out = (float*)d_out;

    const int B = in_sizes[0] / (6 * 37 * 5);           // 32768
    const int waves  = (B + 9) / 10;                    // 10 items per wave
    const int blocks = (waves + 3) / 4;                 // 4 waves per block

    deeparcnet_fused<<<blocks, 256, 0, stream>>>(
        x, conv_w, conv_b, lemb_w, lemb_b, wq, wk, wv, proj_w, proj_b,
        ff1_w, ff1_b, ff2_w, ff2_b, ln1_g, ln1_b, ln2_g, ln2_b,
        lnf_g, lnf_b, fc_w, fc_b, out, B);
}

// Round 2
// 3077.444 us; speedup vs baseline: 1.0834x; 1.0834x over previous
//
#include <hip/hip_runtime.h>
#include <math.h>

// DeepArcNet fused kernel, R2: spill-free restructure.
// Mapping: one wave = 10 items, one lane = (item, token c in 0..5); lanes
// 60..63 idle. Per-lane register state kept <= ~160 floats:
//   - q and v are never materialized: q_d / v_d are computed on the fly
//     (68-FMA dot with SGPR weights) and consumed immediately via 6 shfls.
//   - proj+residual and ff2+residual write IN PLACE into h (they read only
//     attn / z, and h only elementwise) -- no y[68] temp.
// Weights are wave-uniform -> scalar loads (SGPR operand FMAs).
// No LDS, no barriers; cross-token traffic via ds_bpermute (__shfl).

#define EMBD 68
#define NTOK 6
#define HEADD 34

__device__ __forceinline__ float dot68(const float (&h)[EMBD],
                                       const float* __restrict__ w) {
    float a = 0.f;
#pragma unroll
    for (int e = 0; e < EMBD; ++e) a = fmaf(h[e], w[e], a);
    return a;
}

__device__ __forceinline__ void ln68_ip(float (&v)[EMBD],
                                        const float* __restrict__ g,
                                        const float* __restrict__ b) {
    float s1 = 0.f;
#pragma unroll
    for (int e = 0; e < EMBD; ++e) s1 += v[e];
    const float m = s1 * (1.0f / 68.0f);
    float s2 = 0.f;
#pragma unroll
    for (int e = 0; e < EMBD; ++e) { const float d = v[e] - m; s2 = fmaf(d, d, s2); }
    const float rs = rsqrtf(s2 * (1.0f / 68.0f) + 1e-5f);
#pragma unroll
    for (int e = 0; e < EMBD; ++e) v[e] = (v[e] - m) * rs * g[e] + b[e];
}

__global__ __launch_bounds__(256, 2)
void deeparcnet_fused(const float* __restrict__ x,        // [B,6,37,5]
                      const float* __restrict__ conv_w,   // [6,1,5,5]
                      const float* __restrict__ conv_b,   // [6]
                      const float* __restrict__ lemb_w,   // [6,4]
                      const float* __restrict__ lemb_b,   // [6,4]
                      const float* __restrict__ wq,       // [2,2,34,68]
                      const float* __restrict__ wk,
                      const float* __restrict__ wv,
                      const float* __restrict__ proj_w,   // [2,68,68]
                      const float* __restrict__ proj_b,   // [2,68]
                      const float* __restrict__ ff1_w,    // [2,34,68]
                      const float* __restrict__ ff1_b,    // [2,34]
                      const float* __restrict__ ff2_w,    // [2,68,34]
                      const float* __restrict__ ff2_b,    // [2,68]
                      const float* __restrict__ ln1_g, const float* __restrict__ ln1_b,
                      const float* __restrict__ ln2_g, const float* __restrict__ ln2_b,
                      const float* __restrict__ lnf_g, const float* __restrict__ lnf_b,
                      const float* __restrict__ fc_w,     // [6,408]
                      const float* __restrict__ fc_b,     // [6]
                      float* __restrict__ out,            // [B,6]
                      int B)
{
    const int lane = threadIdx.x & 63;
    const int wid  = blockIdx.x * (blockDim.x >> 6) + (threadIdx.x >> 6);
    const int sub  = lane / 6;          // item slot in wave: 0..10
    const int c    = lane - sub * 6;    // token / conv channel: 0..5
    const int item = wid * 10 + sub;
    const bool active = (sub < 10) && (item < B);
    const int it = active ? item : 0;   // clamp for safe loads
    const int base_lane = sub * 6;

    // ---------------- conv encode: [37,5] -> relu -> xc[17] ----------------
    float h[EMBD];
    {
        float xw[25];
#pragma unroll
        for (int k = 0; k < 25; ++k) xw[k] = conv_w[c * 25 + k];
        const float cb = conv_b[c];
        const float* xp = x + (size_t)(it * 6 + c) * 185;

        float xc[17];
#pragma unroll
        for (int i = 0; i < 17; ++i) {
            float a = cb;
#pragma unroll
            for (int k = 0; k < 25; ++k) a = fmaf(xp[i * 10 + k], xw[k], a);
            xc[i] = fmaxf(a, 0.0f);
        }

        // ------------- linear embed (1->4) + sinusoidal pos ---------------
        const float lw0 = lemb_w[c * 4 + 0], lw1 = lemb_w[c * 4 + 1];
        const float lw2 = lemb_w[c * 4 + 2], lw3 = lemb_w[c * 4 + 3];
        const float lb0 = lemb_b[c * 4 + 0], lb1 = lemb_b[c * 4 + 1];
        const float lb2 = lemb_b[c * 4 + 2], lb3 = lemb_b[c * 4 + 3];

#pragma unroll
        for (int t = 0; t < 17; ++t) {
            const float tf = (float)t;
            const float a1 = tf * (1.0f / 18.0f);   // freqs = [1, 1/18]
            h[4 * t + 0] = fmaf(xc[t], lw0, lb0) + __sinf(tf);
            h[4 * t + 1] = fmaf(xc[t], lw1, lb1) + __sinf(a1);
            h[4 * t + 2] = fmaf(xc[t], lw2, lb2) + __cosf(tf);
            h[4 * t + 3] = fmaf(xc[t], lw3, lb3) + __cosf(a1);
        }
    }

    const float qscale = 0.16903085094570331f;  // 34^-0.5

    // ---------------- 2 transformer layers (rolled) ------------------------
#pragma unroll 1
    for (int l = 0; l < 2; ++l) {
        const float* Wq = wq + l * (2 * HEADD * EMBD);
        const float* Wk = wk + l * (2 * HEADD * EMBD);
        const float* Wv = wv + l * (2 * HEADD * EMBD);
        const float* Pw = proj_w + l * (EMBD * EMBD);
        const float* Pb = proj_b + l * EMBD;
        const float* W1 = ff1_w + l * (HEADD * EMBD);
        const float* b1 = ff1_b + l * HEADD;
        const float* W2 = ff2_w + l * (EMBD * HEADD);
        const float* b2 = ff2_b + l * EMBD;
        const float* g1 = ln1_g + l * EMBD; const float* e1 = ln1_b + l * EMBD;
        const float* g2 = ln2_g + l * EMBD; const float* e2 = ln2_b + l * EMBD;

        // ---- k[68] (my token's keys, both heads) ----
        float k[EMBD];
#pragma unroll
        for (int o = 0; o < EMBD; ++o) k[o] = dot68(h, Wk + o * EMBD);

        // ---- scores: q_d streamed, consumed immediately ----
        float wei[2][NTOK];
#pragma unroll
        for (int hh = 0; hh < 2; ++hh)
#pragma unroll
            for (int s = 0; s < NTOK; ++s) wei[hh][s] = 0.f;

#pragma unroll
        for (int hh = 0; hh < 2; ++hh) {
#pragma unroll
            for (int d = 0; d < HEADD; ++d) {
                const int o = hh * HEADD + d;
                const float qd = dot68(h, Wq + o * EMBD);
                const float kd = k[o];
#pragma unroll
                for (int s = 0; s < NTOK; ++s)
                    wei[hh][s] = fmaf(qd, __shfl(kd, base_lane + s, 64), wei[hh][s]);
            }
        }

        // ---- softmax (with q-scale folded in) ----
#pragma unroll
        for (int hh = 0; hh < 2; ++hh) {
            float m = wei[hh][0] * qscale;
#pragma unroll
            for (int s = 0; s < NTOK; ++s) { wei[hh][s] *= qscale; m = fmaxf(m, wei[hh][s]); }
            float sum = 0.f;
#pragma unroll
            for (int s = 0; s < NTOK; ++s) { wei[hh][s] = __expf(wei[hh][s] - m); sum += wei[hh][s]; }
            const float r = 1.0f / sum;
#pragma unroll
            for (int s = 0; s < NTOK; ++s) wei[hh][s] *= r;
        }

        // ---- attn: v_d streamed, consumed immediately (k now dead) ----
        float attn[EMBD];
#pragma unroll
        for (int hh = 0; hh < 2; ++hh) {
#pragma unroll
            for (int d = 0; d < HEADD; ++d) {
                const int o = hh * HEADD + d;
                const float vd = dot68(h, Wv + o * EMBD);
                float a = 0.f;
#pragma unroll
                for (int s = 0; s < NTOK; ++s)
                    a = fmaf(wei[hh][s], __shfl(vd, base_lane + s, 64), a);
                attn[o] = a;
            }
        }

        // ---- proj + residual, IN PLACE into h (reads only attn) ----
#pragma unroll
        for (int o = 0; o < EMBD; ++o) {
            float a = Pb[o];
#pragma unroll
            for (int e = 0; e < EMBD; ++e) a = fmaf(attn[e], Pw[o * EMBD + e], a);
            h[o] += a;
        }
        ln68_ip(h, g1, e1);

        // ---- ff1 (relu) ----
        float z[HEADD];
#pragma unroll
        for (int f = 0; f < HEADD; ++f) {
            float a = b1[f];
#pragma unroll
            for (int e = 0; e < EMBD; ++e) a = fmaf(h[e], W1[f * EMBD + e], a);
            z[f] = fmaxf(a, 0.f);
        }

        // ---- ff2 + residual, IN PLACE into h (reads only z) ----
#pragma unroll
        for (int o = 0; o < EMBD; ++o) {
            float a = b2[o];
#pragma unroll
            for (int f = 0; f < HEADD; ++f) a = fmaf(z[f], W2[o * HEADD + f], a);
            h[o] += a;
        }
        ln68_ip(h, g2, e2);
    }

    // ---------------- final LN ----------------
    ln68_ip(h, lnf_g, lnf_b);

    // ---------------- fc head ----------------
    float p[NTOK];
#pragma unroll
    for (int o = 0; o < NTOK; ++o) {
        float a = 0.f;
#pragma unroll
        for (int e = 0; e < EMBD; ++e)
            a = fmaf(h[e], fc_w[o * 408 + c * EMBD + e], a);
        p[o] = a;
    }
    float tot[NTOK];
#pragma unroll
    for (int o = 0; o < NTOK; ++o) {
        float a = 0.f;
#pragma unroll
        for (int t = 0; t < NTOK; ++t) a += __shfl(p[o], base_lane + t, 64);
        tot[o] = a + fc_b[o];
    }
    float myout = tot[0];
    if (c == 1) myout = tot[1];
    if (c == 2) myout = tot[2];
    if (c == 3) myout = tot[3];
    if (c == 4) myout = tot[4];
    if (c == 5) myout = tot[5];
    if (active) out[(size_t)item * 6 + c] = fmaxf(myout, 0.f);
}

extern "C" void kernel_launch(void* const* d_in, const int* in_sizes, int n_in,
                              void* d_out, int out_size, void* d_ws, size_t ws_size,
                              hipStream_t stream) {
    const float* x      = (const float*)d_in[0];
    const float* conv_w = (const float*)d_in[1];
    const float* conv_b = (const float*)d_in[2];
    const float* lemb_w = (const float*)d_in[3];
    const float* lemb_b = (const float*)d_in[4];
    const float* wq     = (const float*)d_in[5];
    const float* wk     = (const float*)d_in[6];
    const float* wv     = (const float*)d_in[7];
    const float* proj_w = (const float*)d_in[8];
    const float* proj_b = (const float*)d_in[9];
    const float* ff1_w  = (const float*)d_in[10];
    const float* ff1_b  = (const float*)d_in[11];
    const float* ff2_w  = (const float*)d_in[12];
    const float* ff2_b  = (const float*)d_in[13];
    const float* ln1_g  = (const float*)d_in[14];
    const float* ln1_b  = (const float*)d_in[15];
    const float* ln2_g  = (const float*)d_in[16];
    const float* ln2_b  = (const float*)d_in[17];
    const float* lnf_g  = (const float*)d_in[18];
    const float* lnf_b  = (const float*)d_in[19];
    const float* fc_w   = (const float*)d_in[20];
    const float* fc_b   = (const float*)d_in[21];
    float* out = (float*)d_out;

    const int B = in_sizes[0] / (6 * 37 * 5);           // 32768
    const int waves  = (B + 9) / 10;                    // 10 items per wave
    const int blocks = (waves + 3) / 4;                 // 4 waves per block

    deeparcnet_fused<<<blocks, 256, 0, stream>>>(
        x, conv_w, conv_b, lemb_w, lemb_b, wq, wk, wv, proj_w, proj_b,
        ff1_w, ff1_b, ff2_w, ff2_b, ln1_g, ln1_b, ln2_g, ln2_b,
        lnf_g, lnf_b, fc_w, fc_b, out, B);
}